// Round 1
// baseline (180.233 us; speedup 1.0000x reference)
//
#include <hip/hip_runtime.h>
#include <hip/hip_bf16.h>
#include <cstdint>

#define BB 32
#define CC 256
#define HF 64
#define WF 64
#define MM 4096   // HF*WF
#define NN 64
#define NCHUNK 8
#define MCHUNK 512

// ws layout (floats):
//   wq      : [B][C][N]            = 524288 floats
//   part    : [B][NCHUNK][N][2]    = 32768 floats  (max, sumexp)
//   trglogit: [B*N]                = 2048 floats
//   trgidx  : [B*N] ints           (after the floats)

__global__ void phase0_gather_norm(const float* __restrict__ fs,
                                   const float* __restrict__ kps_src,
                                   const float* __restrict__ kps_trg,
                                   float* __restrict__ wq,
                                   int* __restrict__ trgidx) {
  int blk = blockIdx.x;          // b*N + n
  int b = blk >> 6, n = blk & 63;
  int c = threadIdx.x;

  float kx = kps_src[blk * 2 + 0];
  float ky = kps_src[blk * 2 + 1];
  int fx = min(max((int)(kx * (1.0f / 16.0f)), 0), WF - 1);
  int fy = min(max((int)(ky * (1.0f / 16.0f)), 0), HF - 1);
  int pix = fy * WF + fx;

  float x = fs[((size_t)b * CC + c) * MM + pix];

  // block reduce sum of squares (256 threads = 4 waves)
  float v = x * x;
  #pragma unroll
  for (int off = 32; off >= 1; off >>= 1) v += __shfl_xor(v, off);
  __shared__ float ssum[4];
  int wid = c >> 6, lane = c & 63;
  if (lane == 0) ssum[wid] = v;
  __syncthreads();
  float tot = ssum[0] + ssum[1] + ssum[2] + ssum[3];
  float inv = 1.0f / fmaxf(sqrtf(tot), 1e-12f);

  wq[((size_t)b * CC + c) * NN + n] = x * inv;

  if (c == 0) {
    float tx = kps_trg[blk * 2 + 0], ty = kps_trg[blk * 2 + 1];
    int gx = min(max((int)(tx * (1.0f / 16.0f)), 0), WF - 1);
    int gy = min(max((int)(ty * (1.0f / 16.0f)), 0), HF - 1);
    trgidx[blk] = gy * WF + gx;
  }
}

__global__ void __launch_bounds__(256)
phaseB_logits(const float* __restrict__ ft,
              const float* __restrict__ wq,
              const int* __restrict__ trgidx,
              float* __restrict__ part,
              float* __restrict__ trglogit) {
  extern __shared__ float smem[];
  float* q_lds = smem;                       // CC*NN floats = 64 KB
  float* partM = smem + CC * NN;             // 4*64
  float* partS = partM + 4 * 64;             // 4*64
  int*   trg_lds = (int*)(partS + 4 * 64);   // 64 ints

  int b = blockIdx.x >> 3;
  int chunk = blockIdx.x & 7;
  int tid = threadIdx.x;

  // stage q-hat for this batch (contiguous, float4)
  const float4* qsrc = (const float4*)(wq + (size_t)b * CC * NN);
  float4* qd = (float4*)q_lds;
  for (int i = tid; i < CC * NN / 4; i += 256) qd[i] = qsrc[i];
  if (tid < 64) trg_lds[tid] = trgidx[b * 64 + tid];
  __syncthreads();

  int m0 = chunk * MCHUNK + tid;   // global m for this thread
  int m1 = m0 + 256;
  const float* fb = ft + (size_t)b * CC * MM;

  float acc0[NN], acc1[NN];
  #pragma unroll
  for (int n = 0; n < NN; ++n) { acc0[n] = 0.f; acc1[n] = 0.f; }
  float ss0 = 0.f, ss1 = 0.f;

  for (int c = 0; c < CC; ++c) {
    float f0 = fb[(size_t)c * MM + m0];
    float f1 = fb[(size_t)c * MM + m1];
    ss0 += f0 * f0;
    ss1 += f1 * f1;
    const float4* qr = (const float4*)(q_lds + c * NN);
    #pragma unroll
    for (int j = 0; j < NN / 4; ++j) {
      float4 q4 = qr[j];
      acc0[4 * j + 0] += q4.x * f0; acc0[4 * j + 1] += q4.y * f0;
      acc0[4 * j + 2] += q4.z * f0; acc0[4 * j + 3] += q4.w * f0;
      acc1[4 * j + 0] += q4.x * f1; acc1[4 * j + 1] += q4.y * f1;
      acc1[4 * j + 2] += q4.z * f1; acc1[4 * j + 3] += q4.w * f1;
    }
  }

  float scale0 = 100.0f / fmaxf(sqrtf(ss0), 1e-12f);  // 1/(nt*T)
  float scale1 = 100.0f / fmaxf(sqrtf(ss1), 1e-12f);
  int wid = tid >> 6, lane = tid & 63;

  // per-wave online softmax partials for each n (fully unrolled: static acc idx)
  #pragma unroll
  for (int n = 0; n < NN; ++n) {
    float l0 = acc0[n] * scale0;
    float l1 = acc1[n] * scale1;
    int t = trg_lds[n];
    if (t == m0) trglogit[b * 64 + n] = l0;   // unique owner across grid
    if (t == m1) trglogit[b * 64 + n] = l1;
    float mx = fmaxf(l0, l1);
    #pragma unroll
    for (int off = 32; off >= 1; off >>= 1) mx = fmaxf(mx, __shfl_xor(mx, off));
    float s = __expf(l0 - mx) + __expf(l1 - mx);
    #pragma unroll
    for (int off = 32; off >= 1; off >>= 1) s += __shfl_xor(s, off);
    if (lane == 0) { partM[wid * 64 + n] = mx; partS[wid * 64 + n] = s; }
  }
  __syncthreads();

  if (tid < 64) {
    int n = tid;
    float gm = -1e30f;
    #pragma unroll
    for (int w = 0; w < 4; ++w) gm = fmaxf(gm, partM[w * 64 + n]);
    float S = 0.f;
    #pragma unroll
    for (int w = 0; w < 4; ++w) S += partS[w * 64 + n] * __expf(partM[w * 64 + n] - gm);
    size_t o = ((size_t)(b * NCHUNK + chunk) * NN + n) * 2;
    part[o] = gm;
    part[o + 1] = S;
  }
}

__global__ void final_reduce(const float* __restrict__ part,
                             const float* __restrict__ trglogit,
                             const void* __restrict__ maskp,
                             float* __restrict__ out) {
  int tid = threadIdx.x;
  __shared__ int flagF, flagB;
  if (tid == 0) { flagF = 0; flagB = 0; }
  __syncthreads();

  // Detect mask upload layout: bool-bytes / int32 / float32 (deterministic).
  const unsigned char* mb = (const unsigned char*)maskp;
  int lf = 0, lb = 0;
  for (int i = tid; i < BB * NN; i += 256) {
    unsigned char v = mb[i];
    int r = i & 3;
    if (r == 3 && v == 0x3F) lf = 1;   // float32 1.0f pattern
    if (r != 0 && v != 0) lb = 1;      // nonzero off-word byte
  }
  if (lf) atomicOr(&flagF, 1);
  if (lb) atomicOr(&flagB, 1);
  __syncthreads();
  int layout = flagF ? 2 : (flagB ? 0 : 1);  // 2=float32, 0=uchar, 1=int32

  float lsum = 0.f, lcnt = 0.f;
  for (int p = tid; p < BB * NN; p += 256) {
    float mval;
    if (layout == 2) mval = ((const float*)maskp)[p];
    else if (layout == 0) mval = (float)mb[p];
    else mval = (float)((const int*)maskp)[p];

    int b = p >> 6, n = p & 63;
    float gm = -1e30f;
    #pragma unroll
    for (int ch = 0; ch < NCHUNK; ++ch)
      gm = fmaxf(gm, part[((size_t)(b * NCHUNK + ch) * NN + n) * 2]);
    float S = 0.f;
    #pragma unroll
    for (int ch = 0; ch < NCHUNK; ++ch) {
      size_t o = ((size_t)(b * NCHUNK + ch) * NN + n) * 2;
      S += part[o + 1] * __expf(part[o] - gm);
    }
    float lse = gm + logf(S);
    float nll = lse - trglogit[p];
    lsum += nll * mval;
    lcnt += mval;
  }

  #pragma unroll
  for (int off = 32; off >= 1; off >>= 1) {
    lsum += __shfl_xor(lsum, off);
    lcnt += __shfl_xor(lcnt, off);
  }
  __shared__ float sS[4], sC[4];
  int wid = tid >> 6, lane = tid & 63;
  if (lane == 0) { sS[wid] = lsum; sC[wid] = lcnt; }
  __syncthreads();
  if (tid == 0) {
    float s = sS[0] + sS[1] + sS[2] + sS[3];
    float cn = sC[0] + sC[1] + sC[2] + sC[3];
    out[0] = s / fmaxf(cn, 1.0f);
  }
}

extern "C" void kernel_launch(void* const* d_in, const int* in_sizes, int n_in,
                              void* d_out, int out_size, void* d_ws, size_t ws_size,
                              hipStream_t stream) {
  const float* fs   = (const float*)d_in[0];
  const float* ft   = (const float*)d_in[1];
  const float* ksrc = (const float*)d_in[2];
  const float* ktrg = (const float*)d_in[3];
  const void*  mask = d_in[4];
  float* out = (float*)d_out;

  float* wq   = (float*)d_ws;
  float* part = wq + (size_t)BB * CC * NN;
  float* trgl = part + (size_t)BB * NCHUNK * NN * 2;
  int* tidx   = (int*)(trgl + BB * NN);

  phase0_gather_norm<<<BB * NN, 256, 0, stream>>>(fs, ksrc, ktrg, wq, tidx);

  size_t lds_bytes = (size_t)(CC * NN + 2 * 4 * 64) * sizeof(float) + 64 * sizeof(int);
  phaseB_logits<<<BB * NCHUNK, 256, lds_bytes, stream>>>(ft, wq, tidx, part, trgl);

  final_reduce<<<1, 256, 0, stream>>>(part, trgl, mask, out);
}

// Round 2
// 55.455 us; speedup vs baseline: 3.2501x; 3.2501x over previous
//
#include <hip/hip_runtime.h>
#include <hip/hip_fp16.h>
#include <cstdint>

#define BB 32
#define CC 256
#define HF 64
#define WF 64
#define MM 4096   // HF*WF
#define NN 64
#define MCHUNKS 32   // m-chunks per batch
#define MPB 128      // m per block (4 waves x 32)
#define KSTEPS 8     // 256 / 32

typedef _Float16 half8 __attribute__((ext_vector_type(8)));
typedef float f32x4 __attribute__((ext_vector_type(4)));

// ws layout:
//   wq   : _Float16[BB * 16384]          fragment-linear q-hat      (1 MB)
//   part : float[BB * MCHUNKS * NN * 2]  per-(b,chunk) (max,sumexp) (512 KB)
//   trgl : float[BB*NN]
//   nll  : float[BB*NN]
//   tidx : int[BB*NN]

// ---------------- phase 0: gather + l2-normalize queries ----------------
__global__ void phase0_gather_norm(const float* __restrict__ fs,
                                   const float* __restrict__ kps_src,
                                   const float* __restrict__ kps_trg,
                                   _Float16* __restrict__ wq,
                                   int* __restrict__ trgidx) {
  int blk = blockIdx.x;          // b*N + n
  int b = blk >> 6, n = blk & 63;
  int c = threadIdx.x;

  float kx = kps_src[blk * 2 + 0];
  float ky = kps_src[blk * 2 + 1];
  int fx = min(max((int)(kx * (1.0f / 16.0f)), 0), WF - 1);
  int fy = min(max((int)(ky * (1.0f / 16.0f)), 0), HF - 1);
  int pix = fy * WF + fx;

  float x = fs[((size_t)b * CC + c) * MM + pix];

  float v = x * x;
  #pragma unroll
  for (int off = 32; off >= 1; off >>= 1) v += __shfl_xor(v, off);
  __shared__ float ssum[4];
  int wid = c >> 6, lane = c & 63;
  if (lane == 0) ssum[wid] = v;
  __syncthreads();
  float tot = ssum[0] + ssum[1] + ssum[2] + ssum[3];
  float inv = 1.0f / fmaxf(sqrtf(tot), 1e-12f);

  // fragment-linear layout for mfma_f32_16x16x32_f16 A-operand:
  // lane l holds A[row=l&15][k=(l>>4)*8+j]; index = ((ks*4+nt)*64 + lane)*8 + j
  int ks = c >> 5, kg = (c >> 3) & 3, j = c & 7;
  int nt = n >> 4, nr = n & 15;
  int lane_f = kg * 16 + nr;
  size_t off = (size_t)b * 16384 + (size_t)((ks * 4 + nt) * 64 + lane_f) * 8 + j;
  wq[off] = (_Float16)(x * inv);

  if (c == 0) {
    float tx = kps_trg[blk * 2 + 0], ty = kps_trg[blk * 2 + 1];
    int gx = min(max((int)(tx * (1.0f / 16.0f)), 0), WF - 1);
    int gy = min(max((int)(ty * (1.0f / 16.0f)), 0), HF - 1);
    trgidx[blk] = gy * WF + gx;
  }
}

// ---------------- phase B: MFMA logits + online softmax partials --------
__global__ void __launch_bounds__(256, 4)
phaseB(const float* __restrict__ ft,
       const _Float16* __restrict__ wq,
       const int* __restrict__ tidx,
       float* __restrict__ part,
       float* __restrict__ trgl) {
  __shared__ _Float16 qf[16384];     // 32 KB: q-hat fragments for this b
  __shared__ int trg_lds[NN];
  __shared__ float pM[4 * NN], pS[4 * NN];

  int b = blockIdx.x >> 5, mc = blockIdx.x & 31;
  int tid = threadIdx.x;

  const uint4* src = (const uint4*)(wq + (size_t)b * 16384);
  uint4* dst = (uint4*)qf;
  #pragma unroll
  for (int i = 0; i < 8; ++i) dst[tid + 256 * i] = src[tid + 256 * i];
  if (tid < NN) trg_lds[tid] = tidx[b * NN + tid];
  __syncthreads();

  int w = tid >> 6, lane = tid & 63, g = lane >> 4, col = lane & 15;
  int m0 = mc * MPB + w * 32;        // this wave's first m
  const float* fb = ft + (size_t)b * CC * MM;
  const float* lb0 = fb + (size_t)(g * 8) * MM + (m0 + col);  // mt=0
  const float* lb1 = lb0 + 16;                                // mt=1

  f32x4 acc[4][2];
  #pragma unroll
  for (int nt = 0; nt < 4; ++nt)
    #pragma unroll
    for (int mt = 0; mt < 2; ++mt) acc[nt][mt] = (f32x4){0.f, 0.f, 0.f, 0.f};
  float ss0 = 0.f, ss1 = 0.f;

  const half8* qv = (const half8*)qf;
  for (int ks = 0; ks < KSTEPS; ++ks) {
    half8 a0 = qv[(ks * 4 + 0) * 64 + lane];
    half8 a1 = qv[(ks * 4 + 1) * 64 + lane];
    half8 a2 = qv[(ks * 4 + 2) * 64 + lane];
    half8 a3 = qv[(ks * 4 + 3) * 64 + lane];

    float f0[8], f1[8];
    #pragma unroll
    for (int j = 0; j < 8; ++j) f0[j] = lb0[(size_t)(ks * 32 + j) * MM];
    #pragma unroll
    for (int j = 0; j < 8; ++j) f1[j] = lb1[(size_t)(ks * 32 + j) * MM];

    half8 b0, b1;
    #pragma unroll
    for (int j = 0; j < 8; ++j) {
      ss0 += f0[j] * f0[j];
      ss1 += f1[j] * f1[j];
      b0[j] = (_Float16)f0[j];
      b1[j] = (_Float16)f1[j];
    }

    acc[0][0] = __builtin_amdgcn_mfma_f32_16x16x32_f16(a0, b0, acc[0][0], 0, 0, 0);
    acc[1][0] = __builtin_amdgcn_mfma_f32_16x16x32_f16(a1, b0, acc[1][0], 0, 0, 0);
    acc[2][0] = __builtin_amdgcn_mfma_f32_16x16x32_f16(a2, b0, acc[2][0], 0, 0, 0);
    acc[3][0] = __builtin_amdgcn_mfma_f32_16x16x32_f16(a3, b0, acc[3][0], 0, 0, 0);
    acc[0][1] = __builtin_amdgcn_mfma_f32_16x16x32_f16(a0, b1, acc[0][1], 0, 0, 0);
    acc[1][1] = __builtin_amdgcn_mfma_f32_16x16x32_f16(a1, b1, acc[1][1], 0, 0, 0);
    acc[2][1] = __builtin_amdgcn_mfma_f32_16x16x32_f16(a2, b1, acc[2][1], 0, 0, 0);
    acc[3][1] = __builtin_amdgcn_mfma_f32_16x16x32_f16(a3, b1, acc[3][1], 0, 0, 0);
  }

  // total sumsq for this lane's m columns (groups hold disjoint c-subsets)
  ss0 += __shfl_xor(ss0, 16); ss0 += __shfl_xor(ss0, 32);
  ss1 += __shfl_xor(ss1, 16); ss1 += __shfl_xor(ss1, 32);
  float scale0 = 100.0f / fmaxf(sqrtf(ss0), 1e-12f);   // 1/(||f||*T)
  float scale1 = 100.0f / fmaxf(sqrtf(ss1), 1e-12f);

  int mA = m0 + col, mB = m0 + 16 + col;

  // per-wave (max, sumexp) partials per n; also capture target logits
  #pragma unroll
  for (int nt = 0; nt < 4; ++nt) {
    #pragma unroll
    for (int r = 0; r < 4; ++r) {
      int n = nt * 16 + g * 4 + r;
      float v0 = acc[nt][0][r] * scale0;
      float v1 = acc[nt][1][r] * scale1;
      int t = trg_lds[n];
      if (t == mA) trgl[b * NN + n] = v0;
      if (t == mB) trgl[b * NN + n] = v1;
      float mx = fmaxf(v0, v1);
      #pragma unroll
      for (int off = 8; off >= 1; off >>= 1) mx = fmaxf(mx, __shfl_xor(mx, off));
      float s = __expf(v0 - mx) + __expf(v1 - mx);
      #pragma unroll
      for (int off = 8; off >= 1; off >>= 1) s += __shfl_xor(s, off);
      if (col == 0) { pM[w * NN + n] = mx; pS[w * NN + n] = s; }
    }
  }
  __syncthreads();

  if (tid < NN) {
    int n = tid;
    float gm = fmaxf(fmaxf(pM[n], pM[NN + n]), fmaxf(pM[2 * NN + n], pM[3 * NN + n]));
    float S = 0.f;
    #pragma unroll
    for (int ww = 0; ww < 4; ++ww)
      S += pS[ww * NN + n] * __expf(pM[ww * NN + n] - gm);
    size_t o = ((size_t)(b * MCHUNKS + mc) * NN + n) * 2;
    part[o] = gm;
    part[o + 1] = S;
  }
}

// ---------------- reduce A: per-(b,n) logsumexp + nll -------------------
__global__ void reduceA(const float* __restrict__ part,
                        const float* __restrict__ trgl,
                        float* __restrict__ nll) {
  int p = blockIdx.x * 256 + threadIdx.x;   // 8 blocks x 256 = 2048
  int b = p >> 6, n = p & 63;
  float gm = -1e30f;
  #pragma unroll
  for (int mc = 0; mc < MCHUNKS; ++mc)
    gm = fmaxf(gm, part[((size_t)(b * MCHUNKS + mc) * NN + n) * 2]);
  float S = 0.f;
  #pragma unroll
  for (int mc = 0; mc < MCHUNKS; ++mc) {
    size_t o = ((size_t)(b * MCHUNKS + mc) * NN + n) * 2;
    S += part[o + 1] * __expf(part[o] - gm);
  }
  nll[p] = gm + logf(S) - trgl[p];
}

// ---------------- reduce B: masked mean ---------------------------------
__global__ void reduceB(const float* __restrict__ nll,
                        const void* __restrict__ maskp,
                        float* __restrict__ out) {
  int tid = threadIdx.x;
  __shared__ int flagF, flagB;
  if (tid == 0) { flagF = 0; flagB = 0; }
  __syncthreads();

  const unsigned char* mb = (const unsigned char*)maskp;
  int lf = 0, lb = 0;
  for (int i = tid; i < BB * NN; i += 256) {
    unsigned char v = mb[i];
    int r = i & 3;
    if (r == 3 && v == 0x3F) lf = 1;   // float32 1.0f pattern
    if (r != 0 && v != 0) lb = 1;      // nonzero off-word byte
  }
  if (lf) atomicOr(&flagF, 1);
  if (lb) atomicOr(&flagB, 1);
  __syncthreads();
  int layout = flagF ? 2 : (flagB ? 0 : 1);  // 2=float32, 0=uchar, 1=int32

  float lsum = 0.f, lcnt = 0.f;
  for (int p = tid; p < BB * NN; p += 256) {
    float mval;
    if (layout == 2) mval = ((const float*)maskp)[p];
    else if (layout == 0) mval = (float)mb[p];
    else mval = (float)((const int*)maskp)[p];
    lsum += nll[p] * mval;
    lcnt += mval;
  }

  #pragma unroll
  for (int off = 32; off >= 1; off >>= 1) {
    lsum += __shfl_xor(lsum, off);
    lcnt += __shfl_xor(lcnt, off);
  }
  __shared__ float sS[4], sC[4];
  int wid = tid >> 6, lane = tid & 63;
  if (lane == 0) { sS[wid] = lsum; sC[wid] = lcnt; }
  __syncthreads();
  if (tid == 0) {
    float s = sS[0] + sS[1] + sS[2] + sS[3];
    float cn = sC[0] + sC[1] + sC[2] + sC[3];
    out[0] = s / fmaxf(cn, 1.0f);
  }
}

extern "C" void kernel_launch(void* const* d_in, const int* in_sizes, int n_in,
                              void* d_out, int out_size, void* d_ws, size_t ws_size,
                              hipStream_t stream) {
  const float* fs   = (const float*)d_in[0];
  const float* ft   = (const float*)d_in[1];
  const float* ksrc = (const float*)d_in[2];
  const float* ktrg = (const float*)d_in[3];
  const void*  mask = d_in[4];
  float* out = (float*)d_out;

  _Float16* wq = (_Float16*)d_ws;                        // BB*16384 halfs
  float* part  = (float*)((char*)d_ws + (size_t)BB * 16384 * 2);
  float* trgl  = part + (size_t)BB * MCHUNKS * NN * 2;
  float* nll   = trgl + BB * NN;
  int* tidx    = (int*)(nll + BB * NN);

  phase0_gather_norm<<<BB * NN, 256, 0, stream>>>(fs, ksrc, ktrg, wq, tidx);
  phaseB<<<BB * MCHUNKS, 256, 0, stream>>>(ft, wq, tidx, part, trgl);
  reduceA<<<BB * NN / 256, 256, 0, stream>>>(part, trgl, nll);
  reduceB<<<1, 256, 0, stream>>>(nll, mask, out);
}